// Round 1
// baseline (167.872 us; speedup 1.0000x reference)
//
#include <hip/hip_runtime.h>
#include <math.h>

#define LDIM 512
#define BDIM 64

// acc layout: acc[b*3+0]=A (num_contacts), acc[b*3+1]=P (sum t*softplus(-x)),
//             acc[b*3+2]=Q (sum (1-t)*softplus(x)), all over the sl x sl prefix.
__global__ __launch_bounds__(256) void bce_main_kernel(
    const float* __restrict__ x, const float* __restrict__ t,
    const int* __restrict__ seq_lens, float* __restrict__ acc) {
  const int b = blockIdx.y;
  const int sl = seq_lens[b];
  if ((int)blockIdx.x * 4 >= sl) return;  // block-uniform early exit

  const int wave = threadIdx.x >> 6;   // 0..3, one row per wave
  const int lane = threadIdx.x & 63;
  const int i = blockIdx.x * 4 + wave;

  float A = 0.f, P = 0.f, Q = 0.f;
  if (i < sl) {
    const size_t base = ((size_t)b * LDIM + (size_t)i) * LDIM;
    const float4* __restrict__ x4 = (const float4*)(x + base);
    const float4* __restrict__ t4 = (const float4*)(t + base);
    const int nvec = sl >> 2;            // full float4s in the j<sl prefix
    for (int v = lane; v < nvec; v += 64) {
      float4 xv = x4[v];
      float4 tv = t4[v];
      const float xs[4] = {xv.x, xv.y, xv.z, xv.w};
      const float ts[4] = {tv.x, tv.y, tv.z, tv.w};
#pragma unroll
      for (int k = 0; k < 4; ++k) {
        const float xx = xs[k];
        const float tt = ts[k];
        const float ax = fabsf(xx);
        const float m  = __logf(1.f + __expf(-ax));   // log(1+e^-|x|)
        const float spn = fmaxf(-xx, 0.f) + m;        // softplus(-x)
        const float spp = fmaxf( xx, 0.f) + m;        // softplus(x) == x+softplus(-x)
        A += tt;
        P += tt * spn;
        Q += (1.f - tt) * spp;
      }
    }
    const int tail = sl & 3;
    if (lane < tail) {
      const int j = (nvec << 2) + lane;
      const float xx = x[base + j];
      const float tt = t[base + j];
      const float ax = fabsf(xx);
      const float m  = __logf(1.f + __expf(-ax));
      const float spn = fmaxf(-xx, 0.f) + m;
      const float spp = fmaxf( xx, 0.f) + m;
      A += tt;
      P += tt * spn;
      Q += (1.f - tt) * spp;
    }
  }

  // wave (64-lane) shuffle reduction
#pragma unroll
  for (int off = 32; off; off >>= 1) {
    A += __shfl_down(A, off);
    P += __shfl_down(P, off);
    Q += __shfl_down(Q, off);
  }

  __shared__ float s[4][3];
  if (lane == 0) { s[wave][0] = A; s[wave][1] = P; s[wave][2] = Q; }
  __syncthreads();
  if (threadIdx.x == 0) {
    const float a = s[0][0] + s[1][0] + s[2][0] + s[3][0];
    const float p = s[0][1] + s[1][1] + s[2][1] + s[3][1];
    const float q = s[0][2] + s[1][2] + s[2][2] + s[3][2];
    atomicAdd(&acc[b * 3 + 0], a);
    atomicAdd(&acc[b * 3 + 1], p);
    atomicAdd(&acc[b * 3 + 2], q);
  }
}

__global__ __launch_bounds__(64) void bce_final_kernel(
    const float* __restrict__ acc, const int* __restrict__ seq_lens,
    float* __restrict__ out) {
  const int b = threadIdx.x;  // 64 threads, one wave
  const float sl = (float)seq_lens[b];
  const float tp = sl * sl;                     // >= 4096 > 0 always
  const float A = acc[b * 3 + 0];
  const float P = acc[b * 3 + 1];
  const float Q = acc[b * 3 + 2];
  const float density = A / fmaxf(tp, 1.f);
  const float w = fminf(fmaxf(0.01f / (density + 1e-6f), 1.f), 50.f);
  float ps = (w * P + Q) / fmaxf(tp, 1.f);
#pragma unroll
  for (int off = 32; off; off >>= 1) ps += __shfl_down(ps, off);
  if (b == 0) out[0] = ps * (1.f / 64.f);
}

extern "C" void kernel_launch(void* const* d_in, const int* in_sizes, int n_in,
                              void* d_out, int out_size, void* d_ws, size_t ws_size,
                              hipStream_t stream) {
  const float* x = (const float*)d_in[0];
  const float* t = (const float*)d_in[1];
  const int* seq_lens = (const int*)d_in[2];
  float* out = (float*)d_out;
  float* acc = (float*)d_ws;

  hipMemsetAsync(acc, 0, BDIM * 3 * sizeof(float), stream);

  dim3 grid(LDIM / 4, BDIM);  // 128 row-groups x 64 samples
  bce_main_kernel<<<grid, 256, 0, stream>>>(x, t, seq_lens, acc);
  bce_final_kernel<<<1, 64, 0, stream>>>(acc, seq_lens, out);
}

// Round 2
// 134.175 us; speedup vs baseline: 1.2511x; 1.2511x over previous
//
#include <hip/hip_runtime.h>
#include <math.h>

#define LDIM 512
#define BDIM 64
#define BLK_PER_S 32            // blocks per sample
#define ROWSTRIDE (BLK_PER_S*4) // 32 blocks * 4 waves = 128 row stride

// part[b*32 + xblk] = {A, P, Q, 0} partial sums for that block's rows.
__global__ __launch_bounds__(256) void bce_main_kernel(
    const float* __restrict__ x, const float* __restrict__ t,
    const int* __restrict__ seq_lens, float4* __restrict__ part) {
  const int b = blockIdx.y;
  const int xblk = blockIdx.x;
  const int sl = seq_lens[b];
  const int wave = threadIdx.x >> 6;   // 0..3
  const int lane = threadIdx.x & 63;

  float A = 0.f, P = 0.f, Q = 0.f;
  const int nv = (sl + 3) >> 2;        // float4 columns incl. partial tail
  const size_t sbase = (size_t)b * LDIM * LDIM;

  for (int i = xblk * 4 + wave; i < sl; i += ROWSTRIDE) {
    const float4* __restrict__ x4 = (const float4*)(x + sbase + (size_t)i * LDIM);
    const float4* __restrict__ t4 = (const float4*)(t + sbase + (size_t)i * LDIM);
    for (int v = lane; v < nv; v += 64) {
      const float4 xv = x4[v];
      const float4 tv = t4[v];
      const float xs[4] = {xv.x, xv.y, xv.z, xv.w};
      const float ts[4] = {tv.x, tv.y, tv.z, tv.w};
      const int j0 = v << 2;
#pragma unroll
      for (int k = 0; k < 4; ++k) {
        const float on = (j0 + k < sl) ? 1.f : 0.f;  // tail mask (branchless)
        const float xx = xs[k];
        const float tt = ts[k] * on;
        const float ax = fabsf(xx);
        const float m  = __logf(1.f + __expf(-ax));  // log(1+e^-|x|)
        const float spn = fmaxf(-xx, 0.f) + m;       // softplus(-x)
        const float spp = fmaxf( xx, 0.f) + m;       // softplus(x)
        A += tt;
        P += tt * spn;
        Q += (on - tt) * spp;                        // on*(1-t)*softplus(x)
      }
    }
  }

  // wave (64-lane) shuffle reduction
#pragma unroll
  for (int off = 32; off; off >>= 1) {
    A += __shfl_down(A, off);
    P += __shfl_down(P, off);
    Q += __shfl_down(Q, off);
  }

  __shared__ float s[4][3];
  if (lane == 0) { s[wave][0] = A; s[wave][1] = P; s[wave][2] = Q; }
  __syncthreads();
  if (threadIdx.x == 0) {
    float4 p;
    p.x = s[0][0] + s[1][0] + s[2][0] + s[3][0];
    p.y = s[0][1] + s[1][1] + s[2][1] + s[3][1];
    p.z = s[0][2] + s[1][2] + s[2][2] + s[3][2];
    p.w = 0.f;
    part[b * BLK_PER_S + xblk] = p;   // private slot: no atomics, no memset
  }
}

__global__ __launch_bounds__(64) void bce_final_kernel(
    const float4* __restrict__ part, const int* __restrict__ seq_lens,
    float* __restrict__ out) {
  const int b = threadIdx.x;  // 64 threads, one wave
  float A = 0.f, P = 0.f, Q = 0.f;
#pragma unroll
  for (int k = 0; k < BLK_PER_S; ++k) {
    const float4 p = part[b * BLK_PER_S + k];
    A += p.x; P += p.y; Q += p.z;
  }
  const float sl = (float)seq_lens[b];
  const float tp = sl * sl;                      // >= 4096 > 0 always
  const float density = A / fmaxf(tp, 1.f);
  const float w = fminf(fmaxf(0.01f / (density + 1e-6f), 1.f), 50.f);
  float ps = (w * P + Q) / fmaxf(tp, 1.f);
#pragma unroll
  for (int off = 32; off; off >>= 1) ps += __shfl_down(ps, off);
  if (b == 0) out[0] = ps * (1.f / 64.f);
}

extern "C" void kernel_launch(void* const* d_in, const int* in_sizes, int n_in,
                              void* d_out, int out_size, void* d_ws, size_t ws_size,
                              hipStream_t stream) {
  const float* x = (const float*)d_in[0];
  const float* t = (const float*)d_in[1];
  const int* seq_lens = (const int*)d_in[2];
  float* out = (float*)d_out;
  float4* part = (float4*)d_ws;   // 64*32 float4 = 32 KB, fully overwritten

  dim3 grid(BLK_PER_S, BDIM);     // 32 x 64 = 2048 blocks = 8/CU
  bce_main_kernel<<<grid, 256, 0, stream>>>(x, t, seq_lens, part);
  bce_final_kernel<<<1, 64, 0, stream>>>(part, seq_lens, out);
}